// Round 3
// baseline (1402.232 us; speedup 1.0000x reference)
//
#include <hip/hip_runtime.h>

typedef unsigned int uint32;
#define DEV __device__ __forceinline__

// ---- problem dims ----
#define KC 16
#define DZ 64
#define DT 1024
#define NT 2048
#define NI 4096

// ---- output element offsets (return-order concat, float32) ----
#define O_MU_ZT   0
#define O_LV_ZT   131072
#define O_MU_P    262144
#define O_LV_P    263168
#define O_CATES   264192
#define O_MU_ZI   296960
#define O_LV_ZI   4491264
#define O_ZI      8685568
#define O_APRED   12879872
#define O_MU_Y    21268480
#define O_LV_Y    21272576
#define O_AREC    21276672

DEV float wred64(float v){
#pragma unroll
  for (int m = 32; m; m >>= 1) v += __shfl_xor(v, m, 64);
  return v;
}

// ---------------- A: encode_t  (mu_zt, logvar_zt; zt->ws f32) ----------------
__global__ __launch_bounds__(128) void k_encode_t(
    const float* __restrict__ treat, const float* __restrict__ Wmu,
    const float* __restrict__ bmu, const float* __restrict__ Wlv,
    const float* __restrict__ blv, float* __restrict__ out,
    float* __restrict__ ws_zt)
{
  __shared__ float row[DT];
  const int n = blockIdx.x, tid = threadIdx.x;
  const float4* tr = (const float4*)(treat + (size_t)n * DT);
  for (int i = tid; i < DT / 4; i += 128) ((float4*)row)[i] = tr[i];
  __syncthreads();
  const int j = tid & 63;
  const bool isMu = tid < 64;
  const float* W = (isMu ? Wmu : Wlv) + (size_t)j * DT;
  float acc = isMu ? bmu[j] : blv[j];
  const float4* w4 = (const float4*)W;
#pragma unroll 8
  for (int i = 0; i < DT / 4; ++i){
    float4 w = w4[i];
    const float* r = &row[i * 4];
    acc += w.x*r[0] + w.y*r[1] + w.z*r[2] + w.w*r[3];
  }
  if (isMu){ out[O_MU_ZT + n*DZ + j] = acc; ws_zt[n*DZ + j] = acc; }
  else     { out[O_LV_ZT + n*DZ + j] = acc; }
}

// ---------------- B: qc_raw -> cates -> c_sample ----------------
__global__ __launch_bounds__(256) void k_qc(
    const float* __restrict__ mu_p, const float* __restrict__ ws_zt,
    float* __restrict__ out, float* __restrict__ ws_c)
{
  const int tid = threadIdx.x, lane = tid & 63;
  const int row = blockIdx.x * 4 + (tid >> 6);
  const float z = ws_zt[row * DZ + lane];
  const float nz = sqrtf(wred64(z * z));
  float myqc = 0.f;
#pragma unroll
  for (int k = 0; k < KC; ++k){
    float cv  = 5.f * mu_p[k * DZ + lane];
    float dot = wred64(z * cv);
    float nc2 = wred64(cv * cv);
    float qc  = 10.f * dot / fmaxf(nz * sqrtf(nc2), 1e-6f);
    if (lane == k) myqc = qc;
  }
  // softmax over lanes 0..15
  float mx = myqc;
#pragma unroll
  for (int m = 8; m; m >>= 1) mx = fmaxf(mx, __shfl_xor(mx, m, 16));
  float e = __expf(myqc - mx);
  float s = e;
#pragma unroll
  for (int m = 8; m; m >>= 1) s += __shfl_xor(s, m, 16);
  float cates = e / s;
  // second softmax (encode_i applies softmax again)
  float mx2 = cates;
#pragma unroll
  for (int m = 8; m; m >>= 1) mx2 = fmaxf(mx2, __shfl_xor(mx2, m, 16));
  float e2 = __expf(cates - mx2);
  float s2 = e2;
#pragma unroll
  for (int m = 8; m; m >>= 1) s2 += __shfl_xor(s2, m, 16);
  float c2 = e2 / s2;
  if (lane < KC){
    out[O_CATES + row * KC + lane] = cates;
    ws_c[row * KC + lane] = c2;
  }
}

// ---------------- C: encode_i fused GEMM  [NI,NT] @ [NT, 2*K*DZ] ----------------
// B[t, k*64+d] = c_sample[t,k] * W[d,t]   (mu half j<1024, lv half j>=1024)
__global__ __launch_bounds__(256) void k_encode_i(
    const float* __restrict__ ins, const float* __restrict__ Wmu,
    const float* __restrict__ bmu, const float* __restrict__ Wlv,
    const float* __restrict__ blv, const float* __restrict__ ws_c,
    float* __restrict__ out)
{
  __shared__ float As[32][68];   // [t][m]
  __shared__ float Bs[32][68];   // [t][dd]
  __shared__ float csh[NT];      // c_sample column for this block's kk
  const int tid = threadIdx.x;
  const int j0 = blockIdx.x * 64;
  const int n0 = blockIdx.y * 64;
  const bool isMu = (j0 < KC * DZ);
  const int kk = (j0 & (KC * DZ - 1)) >> 6;
  const float* W    = isMu ? Wmu : Wlv;
  const float* bias = isMu ? bmu : blv;

  for (int i = tid; i < NT; i += 256) csh[i] = ws_c[i * KC + kk];

  const int lm = tid >> 2, lq = tid & 3;   // load: row 0..63, t-octet 0..3
  const int tm = tid >> 4, tn = tid & 15;  // compute: 4x4 micro-tile
  float acc[4][4] = {};
  const float4* arow = (const float4*)(ins + (size_t)(n0 + lm) * NT);
  const float4* wrow = (const float4*)(W + (size_t)lm * NT);

  for (int t0 = 0; t0 < NT; t0 += 32){
    __syncthreads();
    float4 a0 = arow[(t0 >> 2) + lq*2], a1 = arow[(t0 >> 2) + lq*2 + 1];
    float4 w0 = wrow[(t0 >> 2) + lq*2], w1 = wrow[(t0 >> 2) + lq*2 + 1];
    const int tb = lq * 8;
    As[tb+0][lm] = a0.x; As[tb+1][lm] = a0.y; As[tb+2][lm] = a0.z; As[tb+3][lm] = a0.w;
    As[tb+4][lm] = a1.x; As[tb+5][lm] = a1.y; As[tb+6][lm] = a1.z; As[tb+7][lm] = a1.w;
    const float* cb = &csh[t0 + tb];
    Bs[tb+0][lm] = w0.x*cb[0]; Bs[tb+1][lm] = w0.y*cb[1];
    Bs[tb+2][lm] = w0.z*cb[2]; Bs[tb+3][lm] = w0.w*cb[3];
    Bs[tb+4][lm] = w1.x*cb[4]; Bs[tb+5][lm] = w1.y*cb[5];
    Bs[tb+6][lm] = w1.z*cb[6]; Bs[tb+7][lm] = w1.w*cb[7];
    __syncthreads();
#pragma unroll
    for (int t = 0; t < 32; ++t){
      float4 a = *(const float4*)&As[t][tm * 4];
      float4 b = *(const float4*)&Bs[t][tn * 4];
      acc[0][0] += a.x*b.x; acc[0][1] += a.x*b.y; acc[0][2] += a.x*b.z; acc[0][3] += a.x*b.w;
      acc[1][0] += a.y*b.x; acc[1][1] += a.y*b.y; acc[1][2] += a.y*b.z; acc[1][3] += a.y*b.w;
      acc[2][0] += a.z*b.x; acc[2][1] += a.z*b.y; acc[2][2] += a.z*b.z; acc[2][3] += a.z*b.w;
      acc[3][0] += a.w*b.x; acc[3][1] += a.w*b.y; acc[3][2] += a.w*b.z; acc[3][3] += a.w*b.w;
    }
  }
  const int obase = isMu ? O_MU_ZI : O_LV_ZI;
#pragma unroll
  for (int i = 0; i < 4; ++i){
    const int n = n0 + tm * 4 + i;
    const int dd = tn * 4;
    float4 v;
    v.x = acc[i][0] + bias[dd+0];
    v.y = acc[i][1] + bias[dd+1];
    v.z = acc[i][2] + bias[dd+2];
    v.w = acc[i][3] + bias[dd+3];
    const size_t idx = (size_t)kk * (NI * DZ) + (size_t)n * DZ + dd;
    *(float4*)&out[obase + idx] = v;
    if (isMu) *(float4*)&out[O_ZI + idx] = v;   // zi == mu_zi (eval mode)
  }
}

// ---------------- D: decoder  a_pred[n,t] = sum_k sigmoid(zi_k . zt_t) * c[t,k] ----------------
__global__ __launch_bounds__(256) void k_decoder(
    const float* __restrict__ ws_zt, const float* __restrict__ ws_c,
    const float* __restrict__ muZi, float* __restrict__ out)
{
  __shared__ float Ts[64][68];   // zt   [t][d]
  __shared__ float Zs[64][68];   // zi_k [n][d]
  __shared__ float Cs[64][16];   // c_sample [t][k]
  const int tid = threadIdx.x;
  const int t0 = blockIdx.x * 64;
  const int n0 = blockIdx.y * 64;
  for (int i = tid; i < 64 * 64; i += 256){ int t = i >> 6, d = i & 63; Ts[t][d] = ws_zt[(t0 + t) * DZ + d]; }
  for (int i = tid; i < 64 * 16; i += 256){ int t = i >> 4, k = i & 15; Cs[t][k] = ws_c[(t0 + t) * KC + k]; }
  const int lm = tid >> 2, lq = tid & 3;
  const int tm = tid >> 4, tn = tid & 15;
  float acc[4][4] = {};
  for (int k = 0; k < KC; ++k){
    __syncthreads();
    const float4* zr = (const float4*)(muZi + (size_t)k * (NI * DZ) + (size_t)(n0 + lm) * DZ + lq * 16);
    float4 z0 = zr[0], z1 = zr[1], z2 = zr[2], z3 = zr[3];
    *(float4*)&Zs[lm][lq*16 + 0]  = z0;
    *(float4*)&Zs[lm][lq*16 + 4]  = z1;
    *(float4*)&Zs[lm][lq*16 + 8]  = z2;
    *(float4*)&Zs[lm][lq*16 + 12] = z3;
    __syncthreads();
    float l[4][4] = {};
#pragma unroll
    for (int d = 0; d < 64; d += 4){
      float4 zv[4], tv[4];
#pragma unroll
      for (int i = 0; i < 4; ++i) zv[i] = *(const float4*)&Zs[tm*4 + i][d];
#pragma unroll
      for (int j = 0; j < 4; ++j) tv[j] = *(const float4*)&Ts[tn*4 + j][d];
#pragma unroll
      for (int i = 0; i < 4; ++i)
#pragma unroll
        for (int j = 0; j < 4; ++j)
          l[i][j] += zv[i].x*tv[j].x + zv[i].y*tv[j].y + zv[i].z*tv[j].z + zv[i].w*tv[j].w;
    }
#pragma unroll
    for (int i = 0; i < 4; ++i)
#pragma unroll
      for (int j = 0; j < 4; ++j){
        float sg = 1.f / (1.f + __expf(-l[i][j]));
        acc[i][j] += sg * Cs[tn*4 + j][k];
      }
  }
#pragma unroll
  for (int i = 0; i < 4; ++i){
    float4 v; v.x = acc[i][0]; v.y = acc[i][1]; v.z = acc[i][2]; v.w = acc[i][3];
    *(float4*)&out[O_APRED + (size_t)(n0 + tm*4 + i) * NT + t0 + tn*4] = v;
  }
}

// ---------------- E: a_reconst = sigmoid(zt @ W_arec.T + b) ----------------
__global__ __launch_bounds__(256) void k_arec(
    const float* __restrict__ ws_zt, const float* __restrict__ W,
    const float* __restrict__ bias, float* __restrict__ out)
{
  __shared__ float z[DZ];
  const int n = blockIdx.x, tid = threadIdx.x;
  if (tid < DZ) z[tid] = ws_zt[n * DZ + tid];
  __syncthreads();
  for (int j = tid; j < DT; j += 256){
    const float4* w4 = (const float4*)(W + (size_t)j * DZ);
    float acc = bias[j];
#pragma unroll
    for (int i = 0; i < 16; ++i){
      float4 w = w4[i];
      const float* r = &z[i * 4];
      acc += w.x*r[0] + w.y*r[1] + w.z*r[2] + w.w*r[3];
    }
    out[O_AREC + n * DT + j] = 1.f / (1.f + __expf(-acc));
  }
}

// ---------------- F: predictY (mu_y, logvar_y), 8 instances/block ----------------
__global__ __launch_bounds__(256) void k_predy(
    const float* __restrict__ ins, const float* __restrict__ ws_zt,
    const float* __restrict__ muZi, const float* __restrict__ Wy1,
    const float* __restrict__ by1, const float* __restrict__ Wy2,
    const float* __restrict__ by2, float* __restrict__ out)
{
  __shared__ float azt[8][DZ];
  __shared__ float red[256];
  const int tid = threadIdx.x;
  const int n0 = blockIdx.x * 8;
  const int d = tid & 63, rg = tid >> 6;     // rows rg*2, rg*2+1
  float p0 = 0.f, p1 = 0.f;
  const float* r0 = ins + (size_t)(n0 + rg*2 + 0) * NT;
  const float* r1 = ins + (size_t)(n0 + rg*2 + 1) * NT;
#pragma unroll 4
  for (int t = 0; t < NT; ++t){
    float zv = ws_zt[t * DZ + d];
    p0 += r0[t] * zv;
    p1 += r1[t] * zv;
  }
  azt[rg*2 + 0][d] = p0;
  azt[rg*2 + 1][d] = p1;
  __syncthreads();
  for (int r = 0; r < 8; ++r){
    float part = 0.f;
    for (int j = tid; j < KC * DZ; j += 256){
      const float4* w4 = (const float4*)(Wy1 + (size_t)j * DZ);
      float rep = by1[j];
      const float* a = azt[r];
#pragma unroll
      for (int i = 0; i < 16; ++i){
        float4 w = w4[i];
        const float* rr = &a[i * 4];
        rep += w.x*rr[0] + w.y*rr[1] + w.z*rr[2] + w.w*rr[3];
      }
      float zv = muZi[(size_t)(j >> 6) * (NI * DZ) + (size_t)(n0 + r) * DZ + (j & 63)];
      part += rep * zv + zv * Wy2[j];
    }
    red[tid] = part;
    __syncthreads();
    for (int s = 128; s; s >>= 1){ if (tid < s) red[tid] += red[tid + s]; __syncthreads(); }
    if (tid == 0) out[O_MU_Y + n0 + r] = red[0] + by2[0];
    __syncthreads();
  }
  if (tid < 8) out[O_LV_Y + n0 + tid] = 1.0f;
}

// ---------------- G: pass-through copies ----------------
__global__ __launch_bounds__(256) void k_copy(
    const float* __restrict__ mu_p, const float* __restrict__ lv_p,
    float* __restrict__ out)
{
  int i = blockIdx.x * 256 + threadIdx.x;
  if (i < KC * DZ){ out[O_MU_P + i] = mu_p[i]; out[O_LV_P + i] = lv_p[i]; }
}

extern "C" void kernel_launch(void* const* d_in, const int* in_sizes, int n_in,
                              void* d_out, int out_size, void* d_ws, size_t ws_size,
                              hipStream_t stream)
{
  (void)in_sizes; (void)n_in; (void)out_size; (void)ws_size;
  const float* ins   = (const float*)d_in[0];
  const float* treat = (const float*)d_in[1];
  const float* Wmzt  = (const float*)d_in[2];
  const float* bmzt  = (const float*)d_in[3];
  const float* Wlzt  = (const float*)d_in[4];
  const float* blzt  = (const float*)d_in[5];
  const float* Warec = (const float*)d_in[6];
  const float* barec = (const float*)d_in[7];
  const float* Wmzi  = (const float*)d_in[8];
  const float* bmzi  = (const float*)d_in[9];
  const float* Wlzi  = (const float*)d_in[10];
  const float* blzi  = (const float*)d_in[11];
  const float* mu_p  = (const float*)d_in[12];
  const float* lv_p  = (const float*)d_in[13];
  const float* Wy1   = (const float*)d_in[14];
  const float* by1   = (const float*)d_in[15];
  const float* Wy2   = (const float*)d_in[16];
  const float* by2   = (const float*)d_in[17];
  float* out = (float*)d_out;
  float* ws_zt = (float*)d_ws;          // [NT, DZ] f32
  float* ws_c  = ws_zt + NT * DZ;       // [NT, KC] f32 (c_sample)

  k_encode_t<<<NT, 128, 0, stream>>>(treat, Wmzt, bmzt, Wlzt, blzt, out, ws_zt);
  k_qc      <<<NT / 4, 256, 0, stream>>>(mu_p, ws_zt, out, ws_c);
  k_encode_i<<<dim3(32, 64), 256, 0, stream>>>(ins, Wmzi, bmzi, Wlzi, blzi, ws_c, out);
  k_decoder <<<dim3(32, 64), 256, 0, stream>>>(ws_zt, ws_c, out + O_MU_ZI, out);
  k_arec    <<<NT, 256, 0, stream>>>(ws_zt, Warec, barec, out);
  k_predy   <<<NI / 8, 256, 0, stream>>>(ins, ws_zt, out + O_MU_ZI, Wy1, by1, Wy2, by2, out);
  k_copy    <<<4, 256, 0, stream>>>(mu_p, lv_p, out);
}

// Round 6
// 650.952 us; speedup vs baseline: 2.1541x; 2.1541x over previous
//
#include <hip/hip_runtime.h>

typedef unsigned short ushort_t;
typedef unsigned int   uint32;
typedef __attribute__((ext_vector_type(8))) short short8;
typedef __attribute__((ext_vector_type(4))) float f32x4;

#define DEV __device__ __forceinline__

// ---- problem dims ----
#define KC 16
#define DZ 64
#define DT 1024
#define NT 2048
#define NI 4096
#define KD 1024   // K*DZ

// ---- output element offsets (return-order concat, float32) ----
#define O_MU_ZT   0
#define O_LV_ZT   131072
#define O_MU_P    262144
#define O_LV_P    263168
#define O_CATES   264192
#define O_MU_ZI   296960
#define O_LV_ZI   4491264
#define O_ZI      8685568
#define O_APRED   12879872
#define O_MU_Y    21268480
#define O_LV_Y    21272576
#define O_AREC    21276672

// ---- workspace layout (floats) ----
#define WSF_ZT   0          // [NT*DZ]
#define WSF_C    131072     // [NT*KC]   c_sample (double softmax)
#define WSF_CT   163840     // [KC*NT]   c_sample transposed
#define WSF_AZT  196608     // [NI*DZ]
#define WSF_END  458752
// ushort region starts at WSF_END floats
#define WSU_ZTB  0          // [NT*DZ]   zt bf16
#define WSU_BC   131072     // [2048*NT] Bc bf16
#define WSU_ZIB  4325376    // [KC*NI*DZ] zi bf16

DEV ushort_t f2b(float f){
  uint32 u = __float_as_uint(f);
  u += 0x7fffu + ((u >> 16) & 1u);   // RNE
  return (ushort_t)(u >> 16);
}
DEV uint32 pk(float lo, float hi){  // truncating bf16 pack (2 VALU ops)
  return (__float_as_uint(hi) & 0xffff0000u) | (__float_as_uint(lo) >> 16);
}
DEV float wred64(float v){
#pragma unroll
  for (int m = 32; m; m >>= 1) v += __shfl_xor(v, m, 64);
  return v;
}

// ---------------- A: encode_t ----------------
__global__ __launch_bounds__(128) void k_encode_t(
    const float* __restrict__ treat, const float* __restrict__ Wmu,
    const float* __restrict__ bmu, const float* __restrict__ Wlv,
    const float* __restrict__ blv, float* __restrict__ out,
    float* __restrict__ ws_zt)
{
  __shared__ float row[DT];
  const int n = blockIdx.x, tid = threadIdx.x;
  const float4* tr = (const float4*)(treat + (size_t)n * DT);
  for (int i = tid; i < DT / 4; i += 128) ((float4*)row)[i] = tr[i];
  __syncthreads();
  const int j = tid & 63;
  const bool isMu = tid < 64;
  const float* W = (isMu ? Wmu : Wlv) + (size_t)j * DT;
  float acc = isMu ? bmu[j] : blv[j];
  const float4* w4 = (const float4*)W;
#pragma unroll 8
  for (int i = 0; i < DT / 4; ++i){
    float4 w = w4[i];
    const float* r = &row[i * 4];
    acc += w.x*r[0] + w.y*r[1] + w.z*r[2] + w.w*r[3];
  }
  if (isMu){ out[O_MU_ZT + n*DZ + j] = acc; ws_zt[n*DZ + j] = acc; }
  else     { out[O_LV_ZT + n*DZ + j] = acc; }
}

// ---------------- B: qc -> cates -> c_sample ----------------
__global__ __launch_bounds__(256) void k_qc(
    const float* __restrict__ mu_p, const float* __restrict__ ws_zt,
    float* __restrict__ out, float* __restrict__ ws_c, float* __restrict__ ws_cT)
{
  const int tid = threadIdx.x, lane = tid & 63;
  const int row = blockIdx.x * 4 + (tid >> 6);
  const float z = ws_zt[row * DZ + lane];
  const float nz = sqrtf(wred64(z * z));
  float myqc = 0.f;
#pragma unroll
  for (int k = 0; k < KC; ++k){
    float cv  = 5.f * mu_p[k * DZ + lane];
    float dot = wred64(z * cv);
    float nc2 = wred64(cv * cv);
    float qc  = 10.f * dot / fmaxf(nz * sqrtf(nc2), 1e-6f);
    if (lane == k) myqc = qc;
  }
  float mx = myqc;
#pragma unroll
  for (int m = 8; m; m >>= 1) mx = fmaxf(mx, __shfl_xor(mx, m, 16));
  float e = __expf(myqc - mx);
  float s = e;
#pragma unroll
  for (int m = 8; m; m >>= 1) s += __shfl_xor(s, m, 16);
  float cates = e / s;
  float mx2 = cates;
#pragma unroll
  for (int m = 8; m; m >>= 1) mx2 = fmaxf(mx2, __shfl_xor(mx2, m, 16));
  float e2 = __expf(cates - mx2);
  float s2 = e2;
#pragma unroll
  for (int m = 8; m; m >>= 1) s2 += __shfl_xor(s2, m, 16);
  float c2 = e2 / s2;
  if (lane < KC){
    out[O_CATES + row * KC + lane] = cates;
    ws_c[row * KC + lane] = c2;
    ws_cT[lane * NT + row] = c2;
  }
}

// ---------------- P: prep — build Bc bf16 and ztb bf16 ----------------
__global__ __launch_bounds__(256) void k_prep(
    const float* __restrict__ Wmu, const float* __restrict__ Wlv,
    const float* __restrict__ cT, const float* __restrict__ zt,
    ushort_t* __restrict__ Bc, ushort_t* __restrict__ ztb)
{
  const int bx = blockIdx.x, tid = threadIdx.x;
  if (bx < 2048){
    const int j = bx;
    const bool isMu = j < KD;
    const int kk = (j & (KD-1)) >> 6, d = j & 63;
    const float* W = (isMu ? Wmu : Wlv) + (size_t)d * NT;
    const float* c = cT + (size_t)kk * NT;
    const int t = tid * 8;
    float4 w0 = *(const float4*)(W + t), w1 = *(const float4*)(W + t + 4);
    float4 c0 = *(const float4*)(c + t), c1 = *(const float4*)(c + t + 4);
    ushort_t v[8];
    v[0]=f2b(w0.x*c0.x); v[1]=f2b(w0.y*c0.y); v[2]=f2b(w0.z*c0.z); v[3]=f2b(w0.w*c0.w);
    v[4]=f2b(w1.x*c1.x); v[5]=f2b(w1.y*c1.y); v[6]=f2b(w1.z*c1.z); v[7]=f2b(w1.w*c1.w);
    *(uint4*)(Bc + (size_t)j * NT + t) = *(uint4*)v;
  } else {
    const int g = (bx - 2048) * 256 + tid;   // 0..8191
    const int base = g * 16;                 // NT*DZ = 131072
    const float4* src = (const float4*)(zt + base);
    float4 z0 = src[0], z1 = src[1], z2 = src[2], z3 = src[3];
    ushort_t v[16];
    v[0]=f2b(z0.x); v[1]=f2b(z0.y); v[2]=f2b(z0.z); v[3]=f2b(z0.w);
    v[4]=f2b(z1.x); v[5]=f2b(z1.y); v[6]=f2b(z1.z); v[7]=f2b(z1.w);
    v[8]=f2b(z2.x); v[9]=f2b(z2.y); v[10]=f2b(z2.z); v[11]=f2b(z2.w);
    v[12]=f2b(z3.x); v[13]=f2b(z3.y); v[14]=f2b(z3.z); v[15]=f2b(z3.w);
    *(uint4*)(ztb + base) = *(uint4*)&v[0];
    *(uint4*)(ztb + base + 8) = *(uint4*)&v[8];
  }
}

// ---------------- C: encode_i — bf16 MFMA GEMM [4096x2048] @ Bc^T ----------------
__global__ __launch_bounds__(256) void k_encode_i(
    const float* __restrict__ ins, const ushort_t* __restrict__ Bc,
    const float* __restrict__ bmu, const float* __restrict__ blv,
    float* __restrict__ out, ushort_t* __restrict__ zib)
{
  __shared__ ushort_t As[128*40];   // [row][32k], stride 40 shorts (pad: <=2-way bank)
  __shared__ ushort_t Bs[128*40];
  const int tid = threadIdx.x;
  const int j0 = blockIdx.x * 128, n0 = blockIdx.y * 128;
  const int w = tid >> 6, lane = tid & 63;
  const int wm = w & 1, wn = w >> 1;
  const int l16 = lane & 15, quad = lane >> 4;
  f32x4 acc[4][4] = {};
  const int sr = tid >> 1, sh = tid & 1;
  const float* aG = ins + (size_t)(n0 + sr) * NT;
  const ushort_t* bG = Bc + (size_t)(j0 + sr) * NT;
  ushort_t* asw = &As[sr*40 + sh*16];
  ushort_t* bsw = &Bs[sr*40 + sh*16];
  for (int t0 = 0; t0 < NT; t0 += 32){
    const float4* ap = (const float4*)(aG + t0 + sh*16);
    float4 a0 = ap[0], a1 = ap[1], a2 = ap[2], a3 = ap[3];
    uint4 bv0 = *(const uint4*)(bG + t0 + sh*16);
    uint4 bv1 = *(const uint4*)(bG + t0 + sh*16 + 8);
    __syncthreads();
    uint4 p0, p1;
    p0.x = pk(a0.x,a0.y); p0.y = pk(a0.z,a0.w);
    p0.z = pk(a1.x,a1.y); p0.w = pk(a1.z,a1.w);
    p1.x = pk(a2.x,a2.y); p1.y = pk(a2.z,a2.w);
    p1.z = pk(a3.x,a3.y); p1.w = pk(a3.z,a3.w);
    *(uint4*)asw = p0; *(uint4*)(asw + 8) = p1;
    *(uint4*)bsw = bv0; *(uint4*)(bsw + 8) = bv1;
    __syncthreads();
    short8 af[4], bf[4];
#pragma unroll
    for (int f = 0; f < 4; ++f){
      af[f] = *(const short8*)&As[(wm*64 + f*16 + l16)*40 + quad*8];
      bf[f] = *(const short8*)&Bs[(wn*64 + f*16 + l16)*40 + quad*8];
    }
#pragma unroll
    for (int mf = 0; mf < 4; ++mf)
#pragma unroll
      for (int nf = 0; nf < 4; ++nf)
        acc[mf][nf] = __builtin_amdgcn_mfma_f32_16x16x32_bf16(af[mf], bf[nf], acc[mf][nf], 0, 0, 0);
  }
  const int colBase = j0 + wn*64;
  const bool isMu = colBase < KD;
  const int kk = (colBase & (KD-1)) >> 6;
  const float* bias = isMu ? bmu : blv;
  const size_t zbase = (size_t)kk * (NI*DZ);
#pragma unroll
  for (int mf = 0; mf < 4; ++mf){
    const int r = n0 + wm*64 + mf*16 + quad*4;
#pragma unroll
    for (int nf = 0; nf < 4; ++nf){
      const int d = nf*16 + l16;
      const float bv = bias[d];
#pragma unroll
      for (int reg = 0; reg < 4; ++reg){
        float v = acc[mf][nf][reg] + bv;
        size_t idx = zbase + (size_t)(r + reg)*DZ + d;
        if (isMu){
          out[O_MU_ZI + idx] = v;
          out[O_ZI + idx] = v;
          zib[idx] = f2b(v);
        } else {
          out[O_LV_ZI + idx] = v;
        }
      }
    }
  }
}

// ---------------- D: decoder — per-k MFMA + sigmoid*c epilogue ----------------
__global__ __launch_bounds__(256) void k_decoder(
    const ushort_t* __restrict__ ztb, const ushort_t* __restrict__ zib,
    const float* __restrict__ ws_c, float* __restrict__ out)
{
  __shared__ ushort_t Zt[128*72];   // [t][64d], stride 72 shorts
  __shared__ ushort_t Zi[128*72];   // [n][64d]
  __shared__ float ct[128*17];      // c_sample, padded
  const int tid = threadIdx.x;
  const int t0 = blockIdx.x * 128, n0 = blockIdx.y * 128;
  const int w = tid >> 6, lane = tid & 63;
  const int wm = w & 1, wn = w >> 1;
  const int l16 = lane & 15, quad = lane >> 4;
  const int sr = tid >> 1, sh = tid & 1;
  {
    const uint4* src = (const uint4*)(ztb + (size_t)(t0 + sr)*DZ + sh*32);
    uint4 z0 = src[0], z1 = src[1], z2 = src[2], z3 = src[3];
    uint4* dst = (uint4*)&Zt[sr*72 + sh*32];
    dst[0] = z0; dst[1] = z1; dst[2] = z2; dst[3] = z3;
  }
  for (int i = tid; i < 128*16; i += 256){
    int t = i >> 4, k = i & 15;
    ct[t*17 + k] = ws_c[(size_t)(t0 + t)*KC + k];
  }
  f32x4 accum[4][4] = {};
  for (int k = 0; k < KC; ++k){
    __syncthreads();
    {
      const uint4* src = (const uint4*)(zib + (size_t)k*(NI*DZ) + (size_t)(n0 + sr)*DZ + sh*32);
      uint4 z0 = src[0], z1 = src[1], z2 = src[2], z3 = src[3];
      uint4* dst = (uint4*)&Zi[sr*72 + sh*32];
      dst[0] = z0; dst[1] = z1; dst[2] = z2; dst[3] = z3;
    }
    __syncthreads();
    f32x4 s[4][4] = {};
#pragma unroll
    for (int ks = 0; ks < 2; ++ks){
      short8 af[4], bf[4];
#pragma unroll
      for (int f = 0; f < 4; ++f){
        af[f] = *(const short8*)&Zi[(wm*64 + f*16 + l16)*72 + ks*32 + quad*8];
        bf[f] = *(const short8*)&Zt[(wn*64 + f*16 + l16)*72 + ks*32 + quad*8];
      }
#pragma unroll
      for (int mf = 0; mf < 4; ++mf)
#pragma unroll
        for (int nf = 0; nf < 4; ++nf)
          s[mf][nf] = __builtin_amdgcn_mfma_f32_16x16x32_bf16(af[mf], bf[nf], s[mf][nf], 0, 0, 0);
    }
#pragma unroll
    for (int nf = 0; nf < 4; ++nf){
      const float cv = ct[(nf*16 + l16)*17 + k];
#pragma unroll
      for (int mf = 0; mf < 4; ++mf)
#pragma unroll
        for (int reg = 0; reg < 4; ++reg)
          accum[mf][nf][reg] += cv / (1.f + __expf(-s[mf][nf][reg]));
    }
  }
#pragma unroll
  for (int mf = 0; mf < 4; ++mf){
    const int r = n0 + wm*64 + mf*16 + quad*4;
#pragma unroll
    for (int nf = 0; nf < 4; ++nf){
      const int col = t0 + wn*64 + nf*16 + l16;
#pragma unroll
      for (int reg = 0; reg < 4; ++reg)
        out[O_APRED + (size_t)(r + reg)*NT + col] = accum[mf][nf][reg];
    }
  }
}

// ---------------- E: a_reconst ----------------
__global__ __launch_bounds__(256) void k_arec(
    const float* __restrict__ ws_zt, const float* __restrict__ W,
    const float* __restrict__ bias, float* __restrict__ out)
{
  __shared__ float z[DZ];
  const int n = blockIdx.x, tid = threadIdx.x;
  if (tid < DZ) z[tid] = ws_zt[n * DZ + tid];
  __syncthreads();
  for (int j = tid; j < DT; j += 256){
    const float4* w4 = (const float4*)(W + (size_t)j * DZ);
    float acc = bias[j];
#pragma unroll
    for (int i = 0; i < 16; ++i){
      float4 w = w4[i];
      const float* r = &z[i * 4];
      acc += w.x*r[0] + w.y*r[1] + w.z*r[2] + w.w*r[3];
    }
    out[O_AREC + n * DT + j] = 1.f / (1.f + __expf(-acc));
  }
}

// ---------------- F1: a_zt = ins @ zt  -> ws_azt ----------------
__global__ __launch_bounds__(256) void k_azt(
    const float* __restrict__ ins, const float* __restrict__ ws_zt,
    float* __restrict__ azt)
{
  const int tid = threadIdx.x;
  const int n0 = blockIdx.x * 8;
  const int w = tid >> 6, lane = tid & 63;
  const int r0 = n0 + w*2, r1 = r0 + 1;
  const float* i0 = ins + (size_t)r0 * NT;
  const float* i1 = ins + (size_t)r1 * NT;
  float p0 = 0.f, p1 = 0.f;
#pragma unroll 8
  for (int t = 0; t < NT; ++t){
    float zv = ws_zt[t*DZ + lane];
    p0 += i0[t] * zv;
    p1 += i1[t] * zv;
  }
  azt[(size_t)r0*DZ + lane] = p0;
  azt[(size_t)r1*DZ + lane] = p1;
}

// ---------------- F2: mu_y / logvar_y ----------------
// mu_y[n] = sum_j (azt[n].Wy1[j] + by1[j] + Wy2[j]) * zi[n,j] + by2
__global__ __launch_bounds__(256) void k_muy(
    const float* __restrict__ azt, const float* __restrict__ Wy1,
    const float* __restrict__ by1, const float* __restrict__ Wy2,
    const float* __restrict__ by2, const float* __restrict__ zi_out,
    float* __restrict__ out)
{
  __shared__ float sazt[16][DZ];
  const int tid = threadIdx.x;
  const int n0 = blockIdx.x * 16;
  for (int i = tid; i < 16*DZ; i += 256)
    sazt[i >> 6][i & 63] = azt[(size_t)(n0 + (i >> 6))*DZ + (i & 63)];
  __syncthreads();
  const int w = tid >> 6, lane = tid & 63;
  float s0 = 0.f, s1 = 0.f, s2 = 0.f, s3 = 0.f;
  for (int jj = 0; jj < 16; ++jj){
    const int j = jj*64 + lane;
    const float4* wr = (const float4*)(Wy1 + (size_t)j * DZ);
    float d0 = 0.f, d1 = 0.f, d2 = 0.f, d3 = 0.f;
    const float* a0 = sazt[w*4 + 0];
    const float* a1 = sazt[w*4 + 1];
    const float* a2 = sazt[w*4 + 2];
    const float* a3 = sazt[w*4 + 3];
#pragma unroll
    for (int i = 0; i < 16; ++i){
      float4 wv = wr[i];
      d0 += wv.x*a0[i*4] + wv.y*a0[i*4+1] + wv.z*a0[i*4+2] + wv.w*a0[i*4+3];
      d1 += wv.x*a1[i*4] + wv.y*a1[i*4+1] + wv.z*a1[i*4+2] + wv.w*a1[i*4+3];
      d2 += wv.x*a2[i*4] + wv.y*a2[i*4+1] + wv.z*a2[i*4+2] + wv.w*a2[i*4+3];
      d3 += wv.x*a3[i*4] + wv.y*a3[i*4+1] + wv.z*a3[i*4+2] + wv.w*a3[i*4+3];
    }
    const float add = by1[j] + Wy2[j];
    const size_t zb = (size_t)jj*(NI*DZ) + lane;
    s0 += (d0 + add) * zi_out[zb + (size_t)(n0 + w*4 + 0)*DZ];
    s1 += (d1 + add) * zi_out[zb + (size_t)(n0 + w*4 + 1)*DZ];
    s2 += (d2 + add) * zi_out[zb + (size_t)(n0 + w*4 + 2)*DZ];
    s3 += (d3 + add) * zi_out[zb + (size_t)(n0 + w*4 + 3)*DZ];
  }
  s0 = wred64(s0); s1 = wred64(s1); s2 = wred64(s2); s3 = wred64(s3);
  if (lane == 0){
    const float b = by2[0];
    out[O_MU_Y + n0 + w*4 + 0] = s0 + b;
    out[O_MU_Y + n0 + w*4 + 1] = s1 + b;
    out[O_MU_Y + n0 + w*4 + 2] = s2 + b;
    out[O_MU_Y + n0 + w*4 + 3] = s3 + b;
  }
  if (tid < 16) out[O_LV_Y + n0 + tid] = 1.0f;
}

// ---------------- G: pass-through copies ----------------
__global__ __launch_bounds__(256) void k_copy(
    const float* __restrict__ mu_p, const float* __restrict__ lv_p,
    float* __restrict__ out)
{
  int i = blockIdx.x * 256 + threadIdx.x;
  if (i < KC * DZ){ out[O_MU_P + i] = mu_p[i]; out[O_LV_P + i] = lv_p[i]; }
}

extern "C" void kernel_launch(void* const* d_in, const int* in_sizes, int n_in,
                              void* d_out, int out_size, void* d_ws, size_t ws_size,
                              hipStream_t stream)
{
  (void)in_sizes; (void)n_in; (void)out_size; (void)ws_size;
  const float* ins   = (const float*)d_in[0];
  const float* treat = (const float*)d_in[1];
  const float* Wmzt  = (const float*)d_in[2];
  const float* bmzt  = (const float*)d_in[3];
  const float* Wlzt  = (const float*)d_in[4];
  const float* blzt  = (const float*)d_in[5];
  const float* Warec = (const float*)d_in[6];
  const float* barec = (const float*)d_in[7];
  const float* Wmzi  = (const float*)d_in[8];
  const float* bmzi  = (const float*)d_in[9];
  const float* Wlzi  = (const float*)d_in[10];
  const float* blzi  = (const float*)d_in[11];
  const float* mu_p  = (const float*)d_in[12];
  const float* lv_p  = (const float*)d_in[13];
  const float* Wy1   = (const float*)d_in[14];
  const float* by1   = (const float*)d_in[15];
  const float* Wy2   = (const float*)d_in[16];
  const float* by2   = (const float*)d_in[17];
  float* out = (float*)d_out;
  float* wsf = (float*)d_ws;
  ushort_t* wsu = (ushort_t*)(wsf + WSF_END);

  float* ws_zt  = wsf + WSF_ZT;
  float* ws_c   = wsf + WSF_C;
  float* ws_cT  = wsf + WSF_CT;
  float* ws_azt = wsf + WSF_AZT;
  ushort_t* ztb = wsu + WSU_ZTB;
  ushort_t* Bc  = wsu + WSU_BC;
  ushort_t* zib = wsu + WSU_ZIB;

  k_encode_t<<<NT, 128, 0, stream>>>(treat, Wmzt, bmzt, Wlzt, blzt, out, ws_zt);
  k_qc      <<<NT/4, 256, 0, stream>>>(mu_p, ws_zt, out, ws_c, ws_cT);
  k_prep    <<<2080, 256, 0, stream>>>(Wmzi, Wlzi, ws_cT, ws_zt, Bc, ztb);
  k_encode_i<<<dim3(16, 32), 256, 0, stream>>>(ins, Bc, bmzi, blzi, out, zib);
  k_decoder <<<dim3(16, 32), 256, 0, stream>>>(ztb, zib, ws_c, out);
  k_arec    <<<NT, 256, 0, stream>>>(ws_zt, Warec, barec, out);
  k_azt     <<<NI/8, 256, 0, stream>>>(ins, ws_zt, ws_azt);
  k_muy     <<<NI/16, 256, 0, stream>>>(ws_azt, Wy1, by1, Wy2, by2, out + O_ZI, out);
  k_copy    <<<4, 256, 0, stream>>>(mu_p, lv_p, out);
}

// Round 7
// 532.538 us; speedup vs baseline: 2.6331x; 1.2224x over previous
//
#include <hip/hip_runtime.h>

typedef unsigned short ushort_t;
typedef unsigned int   uint32;
typedef __attribute__((ext_vector_type(8))) short short8;
typedef __attribute__((ext_vector_type(4))) float f32x4;

#define DEV __device__ __forceinline__

// ---- problem dims ----
#define KC 16
#define DZ 64
#define DT 1024
#define NT 2048
#define NI 4096
#define KD 1024   // K*DZ

// ---- output element offsets (return-order concat, float32) ----
#define O_MU_ZT   0
#define O_LV_ZT   131072
#define O_MU_P    262144
#define O_LV_P    263168
#define O_CATES   264192
#define O_MU_ZI   296960
#define O_LV_ZI   4491264
#define O_ZI      8685568
#define O_APRED   12879872
#define O_MU_Y    21268480
#define O_LV_Y    21272576
#define O_AREC    21276672

// ---- workspace layout (floats) ----
#define WSF_ZT   0          // [NT*DZ]
#define WSF_C    131072     // [NT*KC]   c_sample (double softmax)
#define WSF_CT   163840     // [KC*NT]   c_sample transposed
#define WSF_AZT  196608     // [NI*DZ]
#define WSF_END  458752
// ushort region starts at WSF_END floats
#define WSU_ZTB  0          // [NT*DZ]   zt bf16
#define WSU_BC   131072     // [2048*NT] Bc bf16
#define WSU_ZIB  4325376    // [KC*NI*DZ] zi bf16

DEV ushort_t f2b(float f){
  uint32 u = __float_as_uint(f);
  u += 0x7fffu + ((u >> 16) & 1u);   // RNE
  return (ushort_t)(u >> 16);
}
DEV uint32 pk(float lo, float hi){  // truncating bf16 pack (2 VALU ops)
  return (__float_as_uint(hi) & 0xffff0000u) | (__float_as_uint(lo) >> 16);
}
DEV float wred64(float v){
#pragma unroll
  for (int m = 32; m; m >>= 1) v += __shfl_xor(v, m, 64);
  return v;
}

// ---------------- A: encode_t — 8 rows/block, W amortized via LDS rows ----------------
__global__ __launch_bounds__(256) void k_encode_t(
    const float* __restrict__ treat, const float* __restrict__ Wmu,
    const float* __restrict__ bmu, const float* __restrict__ Wlv,
    const float* __restrict__ blv, float* __restrict__ out,
    float* __restrict__ ws_zt)
{
  __shared__ float rowsh[8 * DT];
  const int n0 = blockIdx.x * 8, tid = threadIdx.x;
  const float4* src = (const float4*)(treat + (size_t)n0 * DT);
#pragma unroll
  for (int i = 0; i < 8; ++i)
    ((float4*)rowsh)[tid + i * 256] = src[tid + i * 256];
  __syncthreads();
  const int j = tid & 127, half = tid >> 7;
  const bool isMu = j < 64;
  const int jj = j & 63;
  const float* W = (isMu ? Wmu : Wlv) + (size_t)jj * DT;
  const float bias = isMu ? bmu[jj] : blv[jj];
  float a0 = bias, a1 = bias, a2 = bias, a3 = bias;
  const float4* w4 = (const float4*)W;
  const float4* r0 = (const float4*)&rowsh[(half*4 + 0) * DT];
  const float4* r1 = (const float4*)&rowsh[(half*4 + 1) * DT];
  const float4* r2 = (const float4*)&rowsh[(half*4 + 2) * DT];
  const float4* r3 = (const float4*)&rowsh[(half*4 + 3) * DT];
#pragma unroll 4
  for (int i = 0; i < DT / 4; ++i){
    float4 wv = w4[i];
    float4 v0 = r0[i], v1 = r1[i], v2 = r2[i], v3 = r3[i];
    a0 += wv.x*v0.x + wv.y*v0.y + wv.z*v0.z + wv.w*v0.w;
    a1 += wv.x*v1.x + wv.y*v1.y + wv.z*v1.z + wv.w*v1.w;
    a2 += wv.x*v2.x + wv.y*v2.y + wv.z*v2.z + wv.w*v2.w;
    a3 += wv.x*v3.x + wv.y*v3.y + wv.z*v3.z + wv.w*v3.w;
  }
  float acc[4] = {a0, a1, a2, a3};
#pragma unroll
  for (int r = 0; r < 4; ++r){
    const int row = n0 + half*4 + r;
    if (isMu){ out[O_MU_ZT + row*DZ + jj] = acc[r]; ws_zt[row*DZ + jj] = acc[r]; }
    else     { out[O_LV_ZT + row*DZ + jj] = acc[r]; }
  }
}

// ---------------- B: qc -> cates -> c_sample ----------------
__global__ __launch_bounds__(256) void k_qc(
    const float* __restrict__ mu_p, const float* __restrict__ ws_zt,
    float* __restrict__ out, float* __restrict__ ws_c, float* __restrict__ ws_cT)
{
  const int tid = threadIdx.x, lane = tid & 63;
  const int row = blockIdx.x * 4 + (tid >> 6);
  const float z = ws_zt[row * DZ + lane];
  const float nz = sqrtf(wred64(z * z));
  float myqc = 0.f;
#pragma unroll
  for (int k = 0; k < KC; ++k){
    float cv  = 5.f * mu_p[k * DZ + lane];
    float dot = wred64(z * cv);
    float nc2 = wred64(cv * cv);
    float qc  = 10.f * dot / fmaxf(nz * sqrtf(nc2), 1e-6f);
    if (lane == k) myqc = qc;
  }
  float mx = myqc;
#pragma unroll
  for (int m = 8; m; m >>= 1) mx = fmaxf(mx, __shfl_xor(mx, m, 16));
  float e = __expf(myqc - mx);
  float s = e;
#pragma unroll
  for (int m = 8; m; m >>= 1) s += __shfl_xor(s, m, 16);
  float cates = e / s;
  float mx2 = cates;
#pragma unroll
  for (int m = 8; m; m >>= 1) mx2 = fmaxf(mx2, __shfl_xor(mx2, m, 16));
  float e2 = __expf(cates - mx2);
  float s2 = e2;
#pragma unroll
  for (int m = 8; m; m >>= 1) s2 += __shfl_xor(s2, m, 16);
  float c2 = e2 / s2;
  if (lane < KC){
    out[O_CATES + row * KC + lane] = cates;
    ws_c[row * KC + lane] = c2;
    ws_cT[lane * NT + row] = c2;
  }
}

// ---------------- P: prep — build Bc bf16, ztb bf16, + passthrough copies ----------------
__global__ __launch_bounds__(256) void k_prep(
    const float* __restrict__ Wmu, const float* __restrict__ Wlv,
    const float* __restrict__ cT, const float* __restrict__ zt,
    ushort_t* __restrict__ Bc, ushort_t* __restrict__ ztb,
    const float* __restrict__ mu_p, const float* __restrict__ lv_p,
    float* __restrict__ out)
{
  const int bx = blockIdx.x, tid = threadIdx.x;
  if (bx < 2048){
    const int j = bx;
    const bool isMu = j < KD;
    const int kk = (j & (KD-1)) >> 6, d = j & 63;
    const float* W = (isMu ? Wmu : Wlv) + (size_t)d * NT;
    const float* c = cT + (size_t)kk * NT;
    const int t = tid * 8;
    float4 w0 = *(const float4*)(W + t), w1 = *(const float4*)(W + t + 4);
    float4 c0 = *(const float4*)(c + t), c1 = *(const float4*)(c + t + 4);
    ushort_t v[8];
    v[0]=f2b(w0.x*c0.x); v[1]=f2b(w0.y*c0.y); v[2]=f2b(w0.z*c0.z); v[3]=f2b(w0.w*c0.w);
    v[4]=f2b(w1.x*c1.x); v[5]=f2b(w1.y*c1.y); v[6]=f2b(w1.z*c1.z); v[7]=f2b(w1.w*c1.w);
    *(uint4*)(Bc + (size_t)j * NT + t) = *(uint4*)v;
  } else if (bx < 2080){
    const int g = (bx - 2048) * 256 + tid;   // 0..8191
    const int base = g * 16;                 // NT*DZ = 131072
    const float4* src = (const float4*)(zt + base);
    float4 z0 = src[0], z1 = src[1], z2 = src[2], z3 = src[3];
    ushort_t v[16];
    v[0]=f2b(z0.x); v[1]=f2b(z0.y); v[2]=f2b(z0.z); v[3]=f2b(z0.w);
    v[4]=f2b(z1.x); v[5]=f2b(z1.y); v[6]=f2b(z1.z); v[7]=f2b(z1.w);
    v[8]=f2b(z2.x); v[9]=f2b(z2.y); v[10]=f2b(z2.z); v[11]=f2b(z2.w);
    v[12]=f2b(z3.x); v[13]=f2b(z3.y); v[14]=f2b(z3.z); v[15]=f2b(z3.w);
    *(uint4*)(ztb + base) = *(uint4*)&v[0];
    *(uint4*)(ztb + base + 8) = *(uint4*)&v[8];
  } else {
    const int i = (bx - 2080) * 256 + tid;   // 0..1023
    out[O_MU_P + i] = mu_p[i];
    out[O_LV_P + i] = lv_p[i];
  }
}

// ---------------- C: encode_i — bf16 MFMA GEMM, 64x128 tile, BK=64, reg prefetch ----------------
__global__ __launch_bounds__(256) void k_encode_i(
    const float* __restrict__ ins, const ushort_t* __restrict__ Bc,
    const float* __restrict__ bmu, const float* __restrict__ blv,
    float* __restrict__ out, ushort_t* __restrict__ zib)
{
  __shared__ ushort_t As[64*72];    // [n-row][64k], stride 72 shorts
  __shared__ ushort_t Bs[128*72];   // [j-row][64k]
  const int tid = threadIdx.x;
  const int j0 = blockIdx.x * 128, n0 = blockIdx.y * 64;
  const int w = tid >> 6, lane = tid & 63;
  const int wm = w & 1, wn = w >> 1;
  const int l16 = lane & 15, quad = lane >> 4;
  const int ar = tid >> 2, aq = tid & 3;   // A: 4 threads/row, 16 floats each
  const int br = tid >> 1, bh = tid & 1;   // B: 2 threads/row, 32 shorts each
  const float*    aG = ins + (size_t)(n0 + ar) * NT + aq * 16;
  const ushort_t* bG = Bc  + (size_t)(j0 + br) * NT + bh * 32;
  ushort_t* asw = &As[ar*72 + aq*16];
  ushort_t* bsw = &Bs[br*72 + bh*32];

  f32x4 acc[2][4] = {};
  float4 Ar0, Ar1, Ar2, Ar3;
  uint4  Br0, Br1, Br2, Br3;
  {
    const float4* ap = (const float4*)aG;
    Ar0 = ap[0]; Ar1 = ap[1]; Ar2 = ap[2]; Ar3 = ap[3];
    const uint4* bp = (const uint4*)bG;
    Br0 = bp[0]; Br1 = bp[1]; Br2 = bp[2]; Br3 = bp[3];
  }
  for (int ch = 0; ch < 32; ++ch){
    __syncthreads();
    uint4 p0, p1;
    p0.x = pk(Ar0.x,Ar0.y); p0.y = pk(Ar0.z,Ar0.w);
    p0.z = pk(Ar1.x,Ar1.y); p0.w = pk(Ar1.z,Ar1.w);
    p1.x = pk(Ar2.x,Ar2.y); p1.y = pk(Ar2.z,Ar2.w);
    p1.z = pk(Ar3.x,Ar3.y); p1.w = pk(Ar3.z,Ar3.w);
    *(uint4*)asw = p0; *(uint4*)(asw + 8) = p1;
    *(uint4*)bsw = Br0; *(uint4*)(bsw + 8) = Br1;
    *(uint4*)(bsw + 16) = Br2; *(uint4*)(bsw + 24) = Br3;
    __syncthreads();
    if (ch < 31){
      const float4* ap = (const float4*)(aG + (ch+1)*64);
      Ar0 = ap[0]; Ar1 = ap[1]; Ar2 = ap[2]; Ar3 = ap[3];
      const uint4* bp = (const uint4*)(bG + (ch+1)*64);
      Br0 = bp[0]; Br1 = bp[1]; Br2 = bp[2]; Br3 = bp[3];
    }
#pragma unroll
    for (int ks = 0; ks < 2; ++ks){
      short8 af[2], bf[4];
#pragma unroll
      for (int mf = 0; mf < 2; ++mf)
        af[mf] = *(const short8*)&As[(wm*32 + mf*16 + l16)*72 + ks*32 + quad*8];
#pragma unroll
      for (int nf = 0; nf < 4; ++nf)
        bf[nf] = *(const short8*)&Bs[(wn*64 + nf*16 + l16)*72 + ks*32 + quad*8];
#pragma unroll
      for (int mf = 0; mf < 2; ++mf)
#pragma unroll
        for (int nf = 0; nf < 4; ++nf)
          acc[mf][nf] = __builtin_amdgcn_mfma_f32_16x16x32_bf16(af[mf], bf[nf], acc[mf][nf], 0, 0, 0);
    }
  }
  const int colBase = j0 + wn*64;
  const bool isMu = colBase < KD;
  const int kk = (colBase & (KD-1)) >> 6;
  const float* bias = isMu ? bmu : blv;
  const size_t zbase = (size_t)kk * (NI*DZ);
#pragma unroll
  for (int mf = 0; mf < 2; ++mf){
    const int r = n0 + wm*32 + mf*16 + quad*4;
#pragma unroll
    for (int nf = 0; nf < 4; ++nf){
      const int d = nf*16 + l16;
      const float bv = bias[d];
#pragma unroll
      for (int reg = 0; reg < 4; ++reg){
        float v = acc[mf][nf][reg] + bv;
        size_t idx = zbase + (size_t)(r + reg)*DZ + d;
        if (isMu){
          out[O_MU_ZI + idx] = v;
          out[O_ZI + idx] = v;
          zib[idx] = f2b(v);
        } else {
          out[O_LV_ZI + idx] = v;
        }
      }
    }
  }
}

// ---------------- D: decoder — per-k MFMA, 128x64 tile, reg prefetch ----------------
__global__ __launch_bounds__(256) void k_decoder(
    const ushort_t* __restrict__ ztb, const ushort_t* __restrict__ zib,
    const float* __restrict__ ws_c, float* __restrict__ out)
{
  __shared__ ushort_t Zt[64*72];    // [t][64d]
  __shared__ ushort_t Zi[128*72];   // [n][64d]
  __shared__ float ct[64*17];       // c_sample, padded
  const int tid = threadIdx.x;
  const int t0 = blockIdx.x * 64, n0 = blockIdx.y * 128;
  const int w = tid >> 6, lane = tid & 63;
  const int wm = w & 1, wn = w >> 1;
  const int l16 = lane & 15, quad = lane >> 4;
  const int zr = tid >> 2, zq = tid & 3;   // Zt: 4 threads/row, 16 shorts each
  const int ir = tid >> 1, ih = tid & 1;   // Zi: 2 threads/row, 32 shorts each
  {
    const uint4* src = (const uint4*)(ztb + (size_t)(t0 + zr)*DZ + zq*16);
    uint4 z0 = src[0], z1 = src[1];
    uint4* dst = (uint4*)&Zt[zr*72 + zq*16];
    dst[0] = z0; dst[1] = z1;
  }
  for (int i = tid; i < 64*16; i += 256){
    int t = i >> 4, k = i & 15;
    ct[t*17 + k] = ws_c[(size_t)(t0 + t)*KC + k];
  }
  const ushort_t* iG = zib + (size_t)(n0 + ir)*DZ + ih*32;
  ushort_t* isw = &Zi[ir*72 + ih*32];
  uint4 Zr0, Zr1, Zr2, Zr3;
  {
    const uint4* zp = (const uint4*)iG;
    Zr0 = zp[0]; Zr1 = zp[1]; Zr2 = zp[2]; Zr3 = zp[3];
  }
  f32x4 accum[4][2] = {};
  for (int k = 0; k < KC; ++k){
    __syncthreads();
    *(uint4*)isw = Zr0; *(uint4*)(isw + 8) = Zr1;
    *(uint4*)(isw + 16) = Zr2; *(uint4*)(isw + 24) = Zr3;
    __syncthreads();
    if (k < KC - 1){
      const uint4* zp = (const uint4*)(iG + (size_t)(k+1)*(NI*DZ));
      Zr0 = zp[0]; Zr1 = zp[1]; Zr2 = zp[2]; Zr3 = zp[3];
    }
    f32x4 s[4][2] = {};
#pragma unroll
    for (int ks = 0; ks < 2; ++ks){
      short8 af[4], bf[2];
#pragma unroll
      for (int mf = 0; mf < 4; ++mf)
        af[mf] = *(const short8*)&Zi[(wm*64 + mf*16 + l16)*72 + ks*32 + quad*8];
#pragma unroll
      for (int nf = 0; nf < 2; ++nf)
        bf[nf] = *(const short8*)&Zt[(wn*32 + nf*16 + l16)*72 + ks*32 + quad*8];
#pragma unroll
      for (int mf = 0; mf < 4; ++mf)
#pragma unroll
        for (int nf = 0; nf < 2; ++nf)
          s[mf][nf] = __builtin_amdgcn_mfma_f32_16x16x32_bf16(af[mf], bf[nf], s[mf][nf], 0, 0, 0);
    }
#pragma unroll
    for (int nf = 0; nf < 2; ++nf){
      const float cv = ct[(wn*32 + nf*16 + l16)*17 + k];
#pragma unroll
      for (int mf = 0; mf < 4; ++mf)
#pragma unroll
        for (int reg = 0; reg < 4; ++reg)
          accum[mf][nf][reg] += cv / (1.f + __expf(-s[mf][nf][reg]));
    }
  }
#pragma unroll
  for (int mf = 0; mf < 4; ++mf){
    const int r = n0 + wm*64 + mf*16 + quad*4;
#pragma unroll
    for (int nf = 0; nf < 2; ++nf){
      const int col = t0 + wn*32 + nf*16 + l16;
#pragma unroll
      for (int reg = 0; reg < 4; ++reg)
        out[O_APRED + (size_t)(r + reg)*NT + col] = accum[mf][nf][reg];
    }
  }
}

// ---------------- E: a_reconst — 8 rows/block, W amortized ----------------
__global__ __launch_bounds__(256) void k_arec(
    const float* __restrict__ ws_zt, const float* __restrict__ W,
    const float* __restrict__ bias, float* __restrict__ out)
{
  __shared__ float zsh[8 * DZ];
  const int n0 = blockIdx.x * 8, tid = threadIdx.x;
  if (tid < 128)
    ((float4*)zsh)[tid] = ((const float4*)(ws_zt + (size_t)n0 * DZ))[tid];
  __syncthreads();
#pragma unroll
  for (int jo = 0; jo < 4; ++jo){
    const int j = jo*256 + tid;
    const float4* w4 = (const float4*)(W + (size_t)j * DZ);
    const float b = bias[j];
    float acc[8];
#pragma unroll
    for (int r = 0; r < 8; ++r) acc[r] = b;
#pragma unroll
    for (int i = 0; i < 16; ++i){
      float4 wv = w4[i];
#pragma unroll
      for (int r = 0; r < 8; ++r){
        const float* z = &zsh[r*DZ + i*4];
        acc[r] += wv.x*z[0] + wv.y*z[1] + wv.z*z[2] + wv.w*z[3];
      }
    }
#pragma unroll
    for (int r = 0; r < 8; ++r)
      out[O_AREC + (size_t)(n0 + r)*DT + j] = 1.f / (1.f + __expf(-acc[r]));
  }
}

// ---------------- F1: a_zt = ins @ zt  -> ws_azt ----------------
__global__ __launch_bounds__(256) void k_azt(
    const float* __restrict__ ins, const float* __restrict__ ws_zt,
    float* __restrict__ azt)
{
  const int tid = threadIdx.x;
  const int n0 = blockIdx.x * 8;
  const int w = tid >> 6, lane = tid & 63;
  const int r0 = n0 + w*2, r1 = r0 + 1;
  const float* i0 = ins + (size_t)r0 * NT;
  const float* i1 = ins + (size_t)r1 * NT;
  float p0 = 0.f, p1 = 0.f;
#pragma unroll 8
  for (int t = 0; t < NT; ++t){
    float zv = ws_zt[t*DZ + lane];
    p0 += i0[t] * zv;
    p1 += i1[t] * zv;
  }
  azt[(size_t)r0*DZ + lane] = p0;
  azt[(size_t)r1*DZ + lane] = p1;
}

// ---------------- F2: mu_y / logvar_y ----------------
__global__ __launch_bounds__(256) void k_muy(
    const float* __restrict__ azt, const float* __restrict__ Wy1,
    const float* __restrict__ by1, const float* __restrict__ Wy2,
    const float* __restrict__ by2, const float* __restrict__ zi_out,
    float* __restrict__ out)
{
  __shared__ float sazt[16][DZ];
  const int tid = threadIdx.x;
  const int n0 = blockIdx.x * 16;
  for (int i = tid; i < 16*DZ; i += 256)
    sazt[i >> 6][i & 63] = azt[(size_t)(n0 + (i >> 6))*DZ + (i & 63)];
  __syncthreads();
  const int w = tid >> 6, lane = tid & 63;
  float s0 = 0.f, s1 = 0.f, s2 = 0.f, s3 = 0.f;
  for (int jj = 0; jj < 16; ++jj){
    const int j = jj*64 + lane;
    const float4* wr = (const float4*)(Wy1 + (size_t)j * DZ);
    float d0 = 0.f, d1 = 0.f, d2 = 0.f, d3 = 0.f;
    const float* a0 = sazt[w*4 + 0];
    const float* a1 = sazt[w*4 + 1];
    const float* a2 = sazt[w*4 + 2];
    const float* a3 = sazt[w*4 + 3];
#pragma unroll
    for (int i = 0; i < 16; ++i){
      float4 wv = wr[i];
      d0 += wv.x*a0[i*4] + wv.y*a0[i*4+1] + wv.z*a0[i*4+2] + wv.w*a0[i*4+3];
      d1 += wv.x*a1[i*4] + wv.y*a1[i*4+1] + wv.z*a1[i*4+2] + wv.w*a1[i*4+3];
      d2 += wv.x*a2[i*4] + wv.y*a2[i*4+1] + wv.z*a2[i*4+2] + wv.w*a2[i*4+3];
      d3 += wv.x*a3[i*4] + wv.y*a3[i*4+1] + wv.z*a3[i*4+2] + wv.w*a3[i*4+3];
    }
    const float add = by1[j] + Wy2[j];
    const size_t zb = (size_t)jj*(NI*DZ) + lane;
    s0 += (d0 + add) * zi_out[zb + (size_t)(n0 + w*4 + 0)*DZ];
    s1 += (d1 + add) * zi_out[zb + (size_t)(n0 + w*4 + 1)*DZ];
    s2 += (d2 + add) * zi_out[zb + (size_t)(n0 + w*4 + 2)*DZ];
    s3 += (d3 + add) * zi_out[zb + (size_t)(n0 + w*4 + 3)*DZ];
  }
  s0 = wred64(s0); s1 = wred64(s1); s2 = wred64(s2); s3 = wred64(s3);
  if (lane == 0){
    const float b = by2[0];
    out[O_MU_Y + n0 + w*4 + 0] = s0 + b;
    out[O_MU_Y + n0 + w*4 + 1] = s1 + b;
    out[O_MU_Y + n0 + w*4 + 2] = s2 + b;
    out[O_MU_Y + n0 + w*4 + 3] = s3 + b;
  }
  if (tid < 16) out[O_LV_Y + n0 + tid] = 1.0f;
}

extern "C" void kernel_launch(void* const* d_in, const int* in_sizes, int n_in,
                              void* d_out, int out_size, void* d_ws, size_t ws_size,
                              hipStream_t stream)
{
  (void)in_sizes; (void)n_in; (void)out_size; (void)ws_size;
  const float* ins   = (const float*)d_in[0];
  const float* treat = (const float*)d_in[1];
  const float* Wmzt  = (const float*)d_in[2];
  const float* bmzt  = (const float*)d_in[3];
  const float* Wlzt  = (const float*)d_in[4];
  const float* blzt  = (const float*)d_in[5];
  const float* Warec = (const float*)d_in[6];
  const float* barec = (const float*)d_in[7];
  const float* Wmzi  = (const float*)d_in[8];
  const float* bmzi  = (const float*)d_in[9];
  const float* Wlzi  = (const float*)d_in[10];
  const float* blzi  = (const float*)d_in[11];
  const float* mu_p  = (const float*)d_in[12];
  const float* lv_p  = (const float*)d_in[13];
  const float* Wy1   = (const float*)d_in[14];
  const float* by1   = (const float*)d_in[15];
  const float* Wy2   = (const float*)d_in[16];
  const float* by2   = (const float*)d_in[17];
  float* out = (float*)d_out;
  float* wsf = (float*)d_ws;
  ushort_t* wsu = (ushort_t*)(wsf + WSF_END);

  float* ws_zt  = wsf + WSF_ZT;
  float* ws_c   = wsf + WSF_C;
  float* ws_cT  = wsf + WSF_CT;
  float* ws_azt = wsf + WSF_AZT;
  ushort_t* ztb = wsu + WSU_ZTB;
  ushort_t* Bc  = wsu + WSU_BC;
  ushort_t* zib = wsu + WSU_ZIB;

  k_encode_t<<<NT/8, 256, 0, stream>>>(treat, Wmzt, bmzt, Wlzt, blzt, out, ws_zt);
  k_qc      <<<NT/4, 256, 0, stream>>>(mu_p, ws_zt, out, ws_c, ws_cT);
  k_prep    <<<2084, 256, 0, stream>>>(Wmzi, Wlzi, ws_cT, ws_zt, Bc, ztb, mu_p, lv_p, out);
  k_encode_i<<<dim3(16, 64), 256, 0, stream>>>(ins, Bc, bmzi, blzi, out, zib);
  k_decoder <<<dim3(32, 32), 256, 0, stream>>>(ztb, zib, ws_c, out);
  k_arec    <<<NT/8, 256, 0, stream>>>(ws_zt, Warec, barec, out);
  k_azt     <<<NI/8, 256, 0, stream>>>(ins, ws_zt, ws_azt);
  k_muy     <<<NI/16, 256, 0, stream>>>(ws_azt, Wy1, by1, Wy2, by2, out + O_ZI, out);
}